// Round 24
// baseline (16.017 us; speedup 1.0000x reference)
//
#include <hip/hip_runtime.h>

// Sequential implicit-midpoint solve: y_k = y_{k-1} + DT*f_k - DT*tanh(W s_k),
// s_k = (y_k + y_{k-1})/2, one wave per batch element.
//
// R24 = R23 (15.36us, absmax 0.04443359) with the SEED MFMA ROUND replaced
// by the R7-proven readlane+fdot2 wave matvec (~1000 cyc vs ~3700 for a full
// MFMA round with 2 LDS trips). The seed computes only tcar = tanh(W y0),
// consumed by block-1's iter-1 predictor (iter-2 refines it), so the changed
// rounding path perturbs absmax by <~0.002. MFMA rounds: 10 -> 9.
//
// Structure (R22/R23): pipelined 2-iteration scheme, 16 chains/round, 8-step
// blocks. Round r: chains 0..7 = iter-2 midpoints of block r-1; 8..15 =
// iter-1 midpoints of block r. Finalize block r-1 with iter-2 tanh (exact
// recurrence); build y^1(block r) -> m2'(block r); tcar -> m1'(block r+1).
// Verified machinery: wb B-frags, A-frag addressing (18c+g), MFMA_BLOCK,
// D-layout, fences (mem clobber + sched_barrier 0x7F), saddr + scalar clamps,
// unroll-3 ring renaming, last-round dead-tail guards.
// W pre-scaled by 2*log2(e): tanh(Ws) = 1 - 2/(exp2(u)+1).

#define SDIM 64
#define DT_C 0.05f
#define WSCALE 2.8853900817779268f  // 2*log2(e)
#define FENCE_MASK 0x7F             // DS may not cross; all else may

typedef _Float16 v4h __attribute__((ext_vector_type(4)));
typedef _Float16 h2v __attribute__((ext_vector_type(2)));
typedef float    v4f __attribute__((ext_vector_type(4)));
typedef __fp16   g2  __attribute__((ext_vector_type(2)));

#if defined(__HIP_DEVICE_COMPILE__)
#define MFMA16(A, B, C) __builtin_amdgcn_mfma_f32_16x16x16f16((A), (B), (C), 0, 0, 0)
#else
#define MFMA16(A, B, C) (C)  // host pass parses only
#endif

union H2U  { int i; g2 g; h2v h; };
union V4HU { int2 i2; v4h h; g2 g[2]; };

__device__ __forceinline__ float recip_fast(float x) {
    float r; asm("v_rcp_f32 %0, %1" : "=v"(r) : "v"(x)); return r;
}
__device__ __forceinline__ float exp2_fast(float x) {
    float r; asm("v_exp_f32 %0, %1" : "=v"(r) : "v"(x)); return r;
}
__device__ __forceinline__ int pack_h2i(float a, float b) {
    H2U u; u.g = __builtin_amdgcn_cvt_pkrtz(a, b); return u.i;
}
__device__ __forceinline__ h2v pack_hh(float a, float b) {
    H2U u; u.g = __builtin_amdgcn_cvt_pkrtz(a, b); return u.h;
}
__device__ __forceinline__ h2v int_as_hh(int v) {
    H2U u; u.i = v; return u.h;
}
__device__ __forceinline__ v4h pack_h4(float a, float b, float c, float d) {
    V4HU u;
    u.g[0] = __builtin_amdgcn_cvt_pkrtz(a, b);
    u.g[1] = __builtin_amdgcn_cvt_pkrtz(c, d);
    return u.h;
}
__device__ __forceinline__ v4h i2_as_h4(int2 v) { V4HU u; u.i2 = v; return u.h; }
__device__ __forceinline__ int dpp_nb(float s) {
    // quad_perm [1,0,3,2]: lane l <-> l^1
    return __builtin_amdgcn_update_dpp(0, __float_as_int(s), 0xB1, 0xF, 0xF, true);
}
__device__ __forceinline__ int imin(int a, int b) { return a < b ? a : b; }

#define MFMA_BLOCK(ac0, ac1, ac2, ac3, A0, A1, A2, A3, wb)                  \
    ac0 = MFMA16(A0, wb[0],  ac0);  ac1 = MFMA16(A0, wb[4],  ac1);          \
    ac2 = MFMA16(A0, wb[8],  ac2);  ac3 = MFMA16(A0, wb[12], ac3);          \
    ac0 = MFMA16(A1, wb[1],  ac0);  ac1 = MFMA16(A1, wb[5],  ac1);          \
    ac2 = MFMA16(A1, wb[9],  ac2);  ac3 = MFMA16(A1, wb[13], ac3);          \
    ac0 = MFMA16(A2, wb[2],  ac0);  ac1 = MFMA16(A2, wb[6],  ac1);          \
    ac2 = MFMA16(A2, wb[10], ac2);  ac3 = MFMA16(A2, wb[14], ac3);          \
    ac0 = MFMA16(A3, wb[3],  ac0);  ac1 = MFMA16(A3, wb[7],  ac1);          \
    ac2 = MFMA16(A3, wb[11], ac2);  ac3 = MFMA16(A3, wb[15], ac3)

__global__ __launch_bounds__(64) void rnes_pipe_kernel(
    const float* __restrict__ y0,
    const float* __restrict__ forces,
    const float* __restrict__ W,
    float* __restrict__ out,
    int n, int B)
{
    const int b = blockIdx.x;
    const int l = threadIdx.x;
    const bool odd = (l & 1);

    // B-operand frags (R15-verified): wb[t*4+h] = W[16t+(l&15)][16h+4*(l>>4)+kk]
    v4h wb[16];
    {
        const int co = l & 15, g = l >> 4;
        #pragma unroll
        for (int t = 0; t < 4; ++t) {
            #pragma unroll
            for (int h = 0; h < 4; ++h) {
                const float4 v = *reinterpret_cast<const float4*>(
                    W + (16 * t + co) * 64 + 16 * h + 4 * g);
                wb[t * 4 + h] = pack_h4(WSCALE * v.x, WSCALE * v.y,
                                        WSCALE * v.z, WSCALE * v.w);
            }
        }
    }

    __shared__ __align__(16) int    lds_s[576];    // 16 chains x 36 ints
    __shared__ __align__(16) float4 lds_u4[1024];  // [t'][comp] 16KB

    const int BS = B * SDIM;
    const float* frow = forces + b * SDIM;
    float*       orow = out    + b * SDIM;

    const float y0v = (y0 + b * SDIM)[l];
    orow[l] = y0v;
    float yfin = y0v;

    const int base_s = 36 * (l & 1) + (l >> 1);
    const int abase  = 18 * (l & 15) + (l >> 4);   // int2 units
    const int uw     = (l >> 4) * 256 + (l & 15);  // float4 units

    // ---- SEED: tcar = tanh(W y0) via readlane+fdot2 wave matvec (R7-proven;
    //      replaces a full MFMA round: no LDS trips, no fences) ----
    float tcar;
    {
        h2v wpk[32];  // W row l, packed pairs, scaled; dead after seed
        {
            const float4* Wrow = reinterpret_cast<const float4*>(W + l * SDIM);
            #pragma unroll
            for (int j4 = 0; j4 < 16; ++j4) {
                const float4 v = Wrow[j4];
                wpk[2 * j4 + 0] = pack_hh(WSCALE * v.x, WSCALE * v.y);
                wpk[2 * j4 + 1] = pack_hh(WSCALE * v.z, WSCALE * v.w);
            }
        }
        // even lane 2m packs (y0[2m], y0[2m+1])
        const int nb = dpp_nb(y0v);
        const int pki = pack_h2i(y0v, __int_as_float(nb));

        float a0 = 0.f, a1 = 0.f, a2 = 0.f, a3 = 0.f;
        float a4 = 0.f, a5 = 0.f, a6 = 0.f, a7 = 0.f;
        #pragma unroll
        for (int m = 0; m < 32; m += 8) {
            const int b0 = __builtin_amdgcn_readlane(pki, 2 * (m + 0));
            const int b1 = __builtin_amdgcn_readlane(pki, 2 * (m + 1));
            const int b2 = __builtin_amdgcn_readlane(pki, 2 * (m + 2));
            const int b3 = __builtin_amdgcn_readlane(pki, 2 * (m + 3));
            const int b4 = __builtin_amdgcn_readlane(pki, 2 * (m + 4));
            const int b5 = __builtin_amdgcn_readlane(pki, 2 * (m + 5));
            const int b6 = __builtin_amdgcn_readlane(pki, 2 * (m + 6));
            const int b7 = __builtin_amdgcn_readlane(pki, 2 * (m + 7));
            a0 = __builtin_amdgcn_fdot2(wpk[m + 0], int_as_hh(b0), a0, false);
            a1 = __builtin_amdgcn_fdot2(wpk[m + 1], int_as_hh(b1), a1, false);
            a2 = __builtin_amdgcn_fdot2(wpk[m + 2], int_as_hh(b2), a2, false);
            a3 = __builtin_amdgcn_fdot2(wpk[m + 3], int_as_hh(b3), a3, false);
            a4 = __builtin_amdgcn_fdot2(wpk[m + 4], int_as_hh(b4), a4, false);
            a5 = __builtin_amdgcn_fdot2(wpk[m + 5], int_as_hh(b5), a5, false);
            a6 = __builtin_amdgcn_fdot2(wpk[m + 6], int_as_hh(b6), a6, false);
            a7 = __builtin_amdgcn_fdot2(wpk[m + 7], int_as_hh(b7), a7, false);
        }
        const float u = (((a0 + a1) + (a2 + a3)) + ((a4 + a5) + (a6 + a7)));
        tcar = fmaf(-2.f, recip_fast(exp2_fast(u) + 1.f), 1.f);
    }

    // force blocks: fa = block r-1, fb = block r, fc = block r+1
    float fa[8], fb[8], fc[8];
    #pragma unroll
    for (int j = 0; j < 8; ++j) {
        fb[j] = (frow + (size_t)imin(1 + j, n - 1) * BS)[l];
        fc[j] = (frow + (size_t)imin(9 + j, n - 1) * BS)[l];
        fa[j] = fb[j];  // dummy for r=1 (finalize skipped)
    }

    // m1 = iter-1 midpoints of block 1 (tcar predictor); m2 dummy for r=1
    float m1[8], m2[8];
    {
        float yh = y0v;
        #pragma unroll
        for (int j = 0; j < 8; ++j) {
            const float d = fb[j] - tcar;
            m1[j] = fmaf(0.5f * DT_C, d, yh);
            yh = fmaf(DT_C, d, yh);
            m2[j] = m1[j];
        }
    }

    float* op = orow + BS;                 // row 1
    const int R = ((n - 1) + 7) / 8 + 1;   // n=65 -> 9

    #pragma unroll 3
    for (int r = 1; r <= R; ++r) {
        // prefetch block r+2 forces (only if that block exists; uniform guard)
        float fd[8];
        if (r + 2 <= R) {
            #pragma unroll
            for (int j = 0; j < 8; ++j)
                fd[j] = (frow + (size_t)imin(8 * r + 9 + j, n - 1) * BS)[l];
        } else {
            #pragma unroll
            for (int j = 0; j < 8; ++j) fd[j] = 0.f;
        }

        // pack & write 16 chains: c = 0..7 -> m2[c]; c = 8..15 -> m1[c-8].
        #pragma unroll
        for (int i = 0; i < 8; ++i) {
            const float vE = (i < 4) ? m2[2 * i]     : m1[2 * i - 8];
            const float vO = (i < 4) ? m2[2 * i + 1] : m1[2 * i - 7];
            const float nE = __int_as_float(dpp_nb(vE));
            const float nO = __int_as_float(dpp_nb(vO));
            const int pkE = pack_h2i(vE, nE);
            const int pkO = pack_h2i(nO, vO);
            lds_s[base_s + 72 * i] = odd ? pkO : pkE;
        }
        asm volatile("" ::: "memory");
        __builtin_amdgcn_sched_barrier(FENCE_MASK);

        // A-frags + MFMA (verbatim layouts)
        const int2* s2p = reinterpret_cast<const int2*>(lds_s);
        const v4h a0 = i2_as_h4(s2p[abase + 0]);
        const v4h a1 = i2_as_h4(s2p[abase + 4]);
        const v4h a2 = i2_as_h4(s2p[abase + 8]);
        const v4h a3 = i2_as_h4(s2p[abase + 12]);
        v4f c0 = {0.f, 0.f, 0.f, 0.f}, c1 = c0, c2 = c0, c3 = c0;
        MFMA_BLOCK(c0, c1, c2, c3, a0, a1, a2, a3, wb);

        // u-redistribution: write [t'][comp] float4 (contiguous per instr)
        lds_u4[uw + 0]  = make_float4(c0[0], c0[1], c0[2], c0[3]);
        lds_u4[uw + 16] = make_float4(c1[0], c1[1], c1[2], c1[3]);
        lds_u4[uw + 32] = make_float4(c2[0], c2[1], c2[2], c2[3]);
        lds_u4[uw + 48] = make_float4(c3[0], c3[1], c3[2], c3[3]);
        asm volatile("" ::: "memory");
        __builtin_amdgcn_sched_barrier(FENCE_MASK);

        const float4 q0 = lds_u4[0 * 256 + l];  // chains 0..3  at comp l
        const float4 q1 = lds_u4[1 * 256 + l];  // chains 4..7
        const float4 q2 = lds_u4[2 * 256 + l];  // chains 8..11
        const float4 q3 = lds_u4[3 * 256 + l];  // chains 12..15

        // rr = 1/(exp2(u)+1); chains 0..7 feed finalize, 8..15 feed y1
        float rr[16];
        rr[0]  = recip_fast(exp2_fast(q0.x) + 1.f);
        rr[1]  = recip_fast(exp2_fast(q0.y) + 1.f);
        rr[2]  = recip_fast(exp2_fast(q0.z) + 1.f);
        rr[3]  = recip_fast(exp2_fast(q0.w) + 1.f);
        rr[4]  = recip_fast(exp2_fast(q1.x) + 1.f);
        rr[5]  = recip_fast(exp2_fast(q1.y) + 1.f);
        rr[6]  = recip_fast(exp2_fast(q1.z) + 1.f);
        rr[7]  = recip_fast(exp2_fast(q1.w) + 1.f);
        rr[8]  = recip_fast(exp2_fast(q2.x) + 1.f);
        rr[9]  = recip_fast(exp2_fast(q2.y) + 1.f);
        rr[10] = recip_fast(exp2_fast(q2.z) + 1.f);
        rr[11] = recip_fast(exp2_fast(q2.w) + 1.f);
        rr[12] = recip_fast(exp2_fast(q3.x) + 1.f);
        rr[13] = recip_fast(exp2_fast(q3.y) + 1.f);
        rr[14] = recip_fast(exp2_fast(q3.z) + 1.f);
        rr[15] = recip_fast(exp2_fast(q3.w) + 1.f);

        // FINALIZE block r-1 with iter-2 tanh (exact recurrence) + stores
        if (r >= 2) {
            const int k0 = 8 * (r - 2) + 1;
            #pragma unroll
            for (int j = 0; j < 8; ++j) {
                yfin = fmaf(2.f * DT_C, rr[j], fmaf(DT_C, fa[j], yfin) - DT_C);
                if (k0 + j < n) (op + j * BS)[l] = yfin;
            }
            op += 8 * BS;
        }

        // tail work only if block r exists as a future block (dead on r==R)
        if (r < R) {
            // y^1(block r) with iter-1 tanh; emit iter-2 midpoints m2'
            float yb = yfin;
            #pragma unroll
            for (int j = 0; j < 8; ++j) {
                const float ybn = fmaf(2.f * DT_C, rr[8 + j],
                                       fmaf(DT_C, fb[j], yb) - DT_C);
                m2[j] = 0.5f * (yb + ybn);
                yb = ybn;
            }
            tcar = fmaf(-2.f, rr[15], 1.f);  // t1(block r, step 8)

            // predictor midpoints m1'(block r+1)
            float yh = yb;
            #pragma unroll
            for (int j = 0; j < 8; ++j) {
                const float d = fc[j] - tcar;
                m1[j] = fmaf(0.5f * DT_C, d, yh);
                yh = fmaf(DT_C, d, yh);
            }
        }

        // rotate force blocks (unroll-3 renames these away)
        #pragma unroll
        for (int j = 0; j < 8; ++j) { fa[j] = fb[j]; fb[j] = fc[j]; fc[j] = fd[j]; }
    }
}

extern "C" void kernel_launch(void* const* d_in, const int* in_sizes, int n_in,
                              void* d_out, int out_size, void* d_ws, size_t ws_size,
                              hipStream_t stream) {
    const float* y0     = (const float*)d_in[0];   // (B, S)
    const float* forces = (const float*)d_in[1];   // (n, B, S)
    const float* W      = (const float*)d_in[2];   // (S, S)
    float* out = (float*)d_out;                    // (n, B, S)

    const int BS = in_sizes[0];       // B * S
    const int B  = BS / SDIM;         // 128
    const int n  = in_sizes[1] / BS;  // 65

    rnes_pipe_kernel<<<B, SDIM, 0, stream>>>(y0, forces, W, out, n, B);
}

// Round 25
// 13.962 us; speedup vs baseline: 1.1472x; 1.1472x over previous
//
#include <hip/hip_runtime.h>

// Sequential implicit-midpoint solve: y_k = y_{k-1} + DT*f_k - DT*tanh(W s_k),
// s_k = (y_k + y_{k-1})/2, one wave per batch element.
//
// R25 = R23 (15.36us, absmax 0.04443359; R24's readlane seed reverted) +
// COMPILE-TIME SHAPE SPECIALIZATION for the bench shape (n=65, B=128):
//   - template<int NC, int BSC>; NC=0 selects the runtime-generic path.
//   - specialized: R=9 known -> FULL loop unroll (ring rotation = renaming
//     across all rounds, scalar bookkeeping gone, cross-round store sinking
//     / prefetch hoisting under the 0x7F fences), all guards compile-time,
//     row clamps fold away, BS-immediate addressing on the scalar pipe.
// Same FP ops in the same order -> absmax must stay bit-identical.
//
// Structure (R22/R23): pipelined 2-iteration scheme, 16 chains/round, 8-step
// blocks. Round r: chains 0..7 = iter-2 midpoints of block r-1; 8..15 =
// iter-1 midpoints of block r. Finalize block r-1 with iter-2 tanh (exact
// recurrence); build y^1(block r) -> m2'(block r); tcar -> m1'(block r+1).
// 64 steps = 8 blocks -> 10 MFMA rounds (incl. seed).
// Verified machinery: wb B-frags, A-frag addressing (18c+g), MFMA_BLOCK,
// D-layout, fences (mem clobber + sched_barrier 0x7F), saddr + scalar clamps.
// W pre-scaled by 2*log2(e): tanh(Ws) = 1 - 2/(exp2(u)+1).

#define SDIM 64
#define DT_C 0.05f
#define WSCALE 2.8853900817779268f  // 2*log2(e)
#define FENCE_MASK 0x7F             // DS may not cross; all else may

typedef _Float16 v4h __attribute__((ext_vector_type(4)));
typedef float    v4f __attribute__((ext_vector_type(4)));
typedef __fp16   g2  __attribute__((ext_vector_type(2)));

#if defined(__HIP_DEVICE_COMPILE__)
#define MFMA16(A, B, C) __builtin_amdgcn_mfma_f32_16x16x16f16((A), (B), (C), 0, 0, 0)
#else
#define MFMA16(A, B, C) (C)  // host pass parses only
#endif

union H2U  { int i; g2 g; };
union V4HU { int2 i2; v4h h; g2 g[2]; };

__device__ __forceinline__ float recip_fast(float x) {
    float r; asm("v_rcp_f32 %0, %1" : "=v"(r) : "v"(x)); return r;
}
__device__ __forceinline__ float exp2_fast(float x) {
    float r; asm("v_exp_f32 %0, %1" : "=v"(r) : "v"(x)); return r;
}
__device__ __forceinline__ int pack_h2i(float a, float b) {
    H2U u; u.g = __builtin_amdgcn_cvt_pkrtz(a, b); return u.i;
}
__device__ __forceinline__ v4h pack_h4(float a, float b, float c, float d) {
    V4HU u;
    u.g[0] = __builtin_amdgcn_cvt_pkrtz(a, b);
    u.g[1] = __builtin_amdgcn_cvt_pkrtz(c, d);
    return u.h;
}
__device__ __forceinline__ v4h i2_as_h4(int2 v) { V4HU u; u.i2 = v; return u.h; }
__device__ __forceinline__ int dpp_nb(float s) {
    // quad_perm [1,0,3,2]: lane l <-> l^1
    return __builtin_amdgcn_update_dpp(0, __float_as_int(s), 0xB1, 0xF, 0xF, true);
}
__device__ __forceinline__ int imin(int a, int b) { return a < b ? a : b; }

#define MFMA_BLOCK(ac0, ac1, ac2, ac3, A0, A1, A2, A3, wb)                  \
    ac0 = MFMA16(A0, wb[0],  ac0);  ac1 = MFMA16(A0, wb[4],  ac1);          \
    ac2 = MFMA16(A0, wb[8],  ac2);  ac3 = MFMA16(A0, wb[12], ac3);          \
    ac0 = MFMA16(A1, wb[1],  ac0);  ac1 = MFMA16(A1, wb[5],  ac1);          \
    ac2 = MFMA16(A1, wb[9],  ac2);  ac3 = MFMA16(A1, wb[13], ac3);          \
    ac0 = MFMA16(A2, wb[2],  ac0);  ac1 = MFMA16(A2, wb[6],  ac1);          \
    ac2 = MFMA16(A2, wb[10], ac2);  ac3 = MFMA16(A2, wb[14], ac3);          \
    ac0 = MFMA16(A3, wb[3],  ac0);  ac1 = MFMA16(A3, wb[7],  ac1);          \
    ac2 = MFMA16(A3, wb[11], ac2);  ac3 = MFMA16(A3, wb[15], ac3)

// NC/BSC > 0: compile-time n and row-stride; NC == 0: runtime-generic.
template <int NC, int BSC>
__global__ __launch_bounds__(64) void rnes_pipe_kernel(
    const float* __restrict__ y0,
    const float* __restrict__ forces,
    const float* __restrict__ W,
    float* __restrict__ out,
    int n_rt, int B_rt)
{
    const int n  = (NC > 0) ? NC : n_rt;
    const int BS = (BSC > 0) ? BSC : B_rt * SDIM;

    const int b = blockIdx.x;
    const int l = threadIdx.x;
    const bool odd = (l & 1);

    // B-operand frags (R15-verified): wb[t*4+h] = W[16t+(l&15)][16h+4*(l>>4)+kk]
    v4h wb[16];
    {
        const int co = l & 15, g = l >> 4;
        #pragma unroll
        for (int t = 0; t < 4; ++t) {
            #pragma unroll
            for (int h = 0; h < 4; ++h) {
                const float4 v = *reinterpret_cast<const float4*>(
                    W + (16 * t + co) * 64 + 16 * h + 4 * g);
                wb[t * 4 + h] = pack_h4(WSCALE * v.x, WSCALE * v.y,
                                        WSCALE * v.z, WSCALE * v.w);
            }
        }
    }

    __shared__ __align__(16) int    lds_s[576];    // 16 chains x 36 ints
    __shared__ __align__(16) float4 lds_u4[1024];  // [t'][comp] 16KB

    const float* frow = forces + b * SDIM;
    float*       orow = out    + b * SDIM;

    const float y0v = (y0 + b * SDIM)[l];
    orow[l] = y0v;
    float yfin = y0v;

    const int base_s = 36 * (l & 1) + (l >> 1);
    const int abase  = 18 * (l & 15) + (l >> 4);   // int2 units
    const int uw     = (l >> 4) * 256 + (l & 15);  // float4 units

    // ---- SEED round (MFMA, R23): all 16 chains = y0; tcar = tanh(W y0) ----
    float tcar;
    {
        const float nb = __int_as_float(dpp_nb(y0v));
        const int sel = odd ? pack_h2i(nb, y0v) : pack_h2i(y0v, nb);
        #pragma unroll
        for (int i = 0; i < 8; ++i) lds_s[base_s + 72 * i] = sel;
        asm volatile("" ::: "memory");
        __builtin_amdgcn_sched_barrier(FENCE_MASK);

        const int2* s2p = reinterpret_cast<const int2*>(lds_s);
        const v4h a0 = i2_as_h4(s2p[abase + 0]);
        const v4h a1 = i2_as_h4(s2p[abase + 4]);
        const v4h a2 = i2_as_h4(s2p[abase + 8]);
        const v4h a3 = i2_as_h4(s2p[abase + 12]);
        v4f c0 = {0.f, 0.f, 0.f, 0.f}, c1 = c0, c2 = c0, c3 = c0;
        MFMA_BLOCK(c0, c1, c2, c3, a0, a1, a2, a3, wb);

        lds_u4[uw + 0]  = make_float4(c0[0], c0[1], c0[2], c0[3]);
        lds_u4[uw + 16] = make_float4(c1[0], c1[1], c1[2], c1[3]);
        lds_u4[uw + 32] = make_float4(c2[0], c2[1], c2[2], c2[3]);
        lds_u4[uw + 48] = make_float4(c3[0], c3[1], c3[2], c3[3]);
        asm volatile("" ::: "memory");
        __builtin_amdgcn_sched_barrier(FENCE_MASK);

        const float4 q0 = lds_u4[l];  // chains 0..3 at comp l; chain0 = .x
        tcar = fmaf(-2.f, recip_fast(exp2_fast(q0.x) + 1.f), 1.f);
    }

    // force blocks: fa = block r-1, fb = block r, fc = block r+1
    float fa[8], fb[8], fc[8];
    #pragma unroll
    for (int j = 0; j < 8; ++j) {
        fb[j] = (frow + (size_t)imin(1 + j, n - 1) * BS)[l];
        fc[j] = (frow + (size_t)imin(9 + j, n - 1) * BS)[l];
        fa[j] = fb[j];  // dummy for r=1 (finalize skipped)
    }

    // m1 = iter-1 midpoints of block 1 (tcar predictor); m2 dummy for r=1
    float m1[8], m2[8];
    {
        float yh = y0v;
        #pragma unroll
        for (int j = 0; j < 8; ++j) {
            const float d = fb[j] - tcar;
            m1[j] = fmaf(0.5f * DT_C, d, yh);
            yh = fmaf(DT_C, d, yh);
            m2[j] = m1[j];
        }
    }

    float* op = orow + BS;                 // row 1
    const int R = ((n - 1) + 7) / 8 + 1;   // n=65 -> 9

    // full unroll when shape is compile-time (R known), else unroll 3
    #pragma unroll (NC > 0 ? 16 : 3)
    for (int r = 1; r <= R; ++r) {
        // prefetch block r+2 forces (uniform/compile-time guard)
        float fd[8];
        if (r + 2 <= R) {
            #pragma unroll
            for (int j = 0; j < 8; ++j)
                fd[j] = (frow + (size_t)imin(8 * r + 9 + j, n - 1) * BS)[l];
        } else {
            #pragma unroll
            for (int j = 0; j < 8; ++j) fd[j] = 0.f;
        }

        // pack & write 16 chains: c = 0..7 -> m2[c]; c = 8..15 -> m1[c-8].
        #pragma unroll
        for (int i = 0; i < 8; ++i) {
            const float vE = (i < 4) ? m2[2 * i]     : m1[2 * i - 8];
            const float vO = (i < 4) ? m2[2 * i + 1] : m1[2 * i - 7];
            const float nE = __int_as_float(dpp_nb(vE));
            const float nO = __int_as_float(dpp_nb(vO));
            const int pkE = pack_h2i(vE, nE);
            const int pkO = pack_h2i(nO, vO);
            lds_s[base_s + 72 * i] = odd ? pkO : pkE;
        }
        asm volatile("" ::: "memory");
        __builtin_amdgcn_sched_barrier(FENCE_MASK);

        // A-frags + MFMA (verbatim layouts)
        const int2* s2p = reinterpret_cast<const int2*>(lds_s);
        const v4h a0 = i2_as_h4(s2p[abase + 0]);
        const v4h a1 = i2_as_h4(s2p[abase + 4]);
        const v4h a2 = i2_as_h4(s2p[abase + 8]);
        const v4h a3 = i2_as_h4(s2p[abase + 12]);
        v4f c0 = {0.f, 0.f, 0.f, 0.f}, c1 = c0, c2 = c0, c3 = c0;
        MFMA_BLOCK(c0, c1, c2, c3, a0, a1, a2, a3, wb);

        // u-redistribution: write [t'][comp] float4 (contiguous per instr)
        lds_u4[uw + 0]  = make_float4(c0[0], c0[1], c0[2], c0[3]);
        lds_u4[uw + 16] = make_float4(c1[0], c1[1], c1[2], c1[3]);
        lds_u4[uw + 32] = make_float4(c2[0], c2[1], c2[2], c2[3]);
        lds_u4[uw + 48] = make_float4(c3[0], c3[1], c3[2], c3[3]);
        asm volatile("" ::: "memory");
        __builtin_amdgcn_sched_barrier(FENCE_MASK);

        const float4 q0 = lds_u4[0 * 256 + l];  // chains 0..3  at comp l
        const float4 q1 = lds_u4[1 * 256 + l];  // chains 4..7
        const float4 q2 = lds_u4[2 * 256 + l];  // chains 8..11
        const float4 q3 = lds_u4[3 * 256 + l];  // chains 12..15

        // rr = 1/(exp2(u)+1); chains 0..7 feed finalize, 8..15 feed y1
        float rr[16];
        rr[0]  = recip_fast(exp2_fast(q0.x) + 1.f);
        rr[1]  = recip_fast(exp2_fast(q0.y) + 1.f);
        rr[2]  = recip_fast(exp2_fast(q0.z) + 1.f);
        rr[3]  = recip_fast(exp2_fast(q0.w) + 1.f);
        rr[4]  = recip_fast(exp2_fast(q1.x) + 1.f);
        rr[5]  = recip_fast(exp2_fast(q1.y) + 1.f);
        rr[6]  = recip_fast(exp2_fast(q1.z) + 1.f);
        rr[7]  = recip_fast(exp2_fast(q1.w) + 1.f);
        rr[8]  = recip_fast(exp2_fast(q2.x) + 1.f);
        rr[9]  = recip_fast(exp2_fast(q2.y) + 1.f);
        rr[10] = recip_fast(exp2_fast(q2.z) + 1.f);
        rr[11] = recip_fast(exp2_fast(q2.w) + 1.f);
        rr[12] = recip_fast(exp2_fast(q3.x) + 1.f);
        rr[13] = recip_fast(exp2_fast(q3.y) + 1.f);
        rr[14] = recip_fast(exp2_fast(q3.z) + 1.f);
        rr[15] = recip_fast(exp2_fast(q3.w) + 1.f);

        // FINALIZE block r-1 with iter-2 tanh (exact recurrence) + stores
        if (r >= 2) {
            const int k0 = 8 * (r - 2) + 1;
            #pragma unroll
            for (int j = 0; j < 8; ++j) {
                yfin = fmaf(2.f * DT_C, rr[j], fmaf(DT_C, fa[j], yfin) - DT_C);
                if (k0 + j < n) (op + j * BS)[l] = yfin;
            }
            op += 8 * BS;
        }

        // tail work only if block r exists as a future block (dead on r==R)
        if (r < R) {
            // y^1(block r) with iter-1 tanh; emit iter-2 midpoints m2'
            float yb = yfin;
            #pragma unroll
            for (int j = 0; j < 8; ++j) {
                const float ybn = fmaf(2.f * DT_C, rr[8 + j],
                                       fmaf(DT_C, fb[j], yb) - DT_C);
                m2[j] = 0.5f * (yb + ybn);
                yb = ybn;
            }
            tcar = fmaf(-2.f, rr[15], 1.f);  // t1(block r, step 8)

            // predictor midpoints m1'(block r+1)
            float yh = yb;
            #pragma unroll
            for (int j = 0; j < 8; ++j) {
                const float d = fc[j] - tcar;
                m1[j] = fmaf(0.5f * DT_C, d, yh);
                yh = fmaf(DT_C, d, yh);
            }
        }

        // rotate force blocks (unroll renames these away)
        #pragma unroll
        for (int j = 0; j < 8; ++j) { fa[j] = fb[j]; fb[j] = fc[j]; fc[j] = fd[j]; }
    }
}

extern "C" void kernel_launch(void* const* d_in, const int* in_sizes, int n_in,
                              void* d_out, int out_size, void* d_ws, size_t ws_size,
                              hipStream_t stream) {
    const float* y0     = (const float*)d_in[0];   // (B, S)
    const float* forces = (const float*)d_in[1];   // (n, B, S)
    const float* W      = (const float*)d_in[2];   // (S, S)
    float* out = (float*)d_out;                    // (n, B, S)

    const int BS = in_sizes[0];       // B * S
    const int B  = BS / SDIM;         // 128
    const int n  = in_sizes[1] / BS;  // 65

    if (n == 65 && BS == 8192) {
        // bench shape: compile-time n / stride, fully unrolled 9-round loop
        rnes_pipe_kernel<65, 8192><<<B, SDIM, 0, stream>>>(y0, forces, W, out, n, B);
    } else {
        rnes_pipe_kernel<0, 0><<<B, SDIM, 0, stream>>>(y0, forces, W, out, n, B);
    }
}